// Round 3
// baseline (454.814 us; speedup 1.0000x reference)
//
#include <hip/hip_runtime.h>
#include <stdint.h>

#define CONF_THR 0.6f
#define IOU_THR  0.45f
#define MAX_WH_F 4096.0f
#define TOPK     1024
#define MAX_DET  300
#define NCLS     80
#define ROW      85
#define APB      128   // anchors per block in K1
#define NMS_P    32    // k_nms prefetch pipeline depth (rows in flight)

typedef unsigned int u32;
typedef unsigned long long u64;

__device__ __forceinline__ u32 f2s(float f) {
    u32 b = __float_as_uint(f);
    return b ^ ((u32)((int)b >> 31) | 0x80000000u);
}
__device__ __forceinline__ float s2f(u32 k) {
    u32 b = (k & 0x80000000u) ? (k ^ 0x80000000u) : ~k;
    return __uint_as_float(b);
}

// ---------------- K1: per-anchor score/cls ----------------
__global__ __launch_bounds__(256) void k_score(const float* __restrict__ pred,
        u32* __restrict__ key, u32* __restrict__ cls, int NA) {
#pragma clang fp contract(off)
    int img = blockIdx.y;
    int a0 = blockIdx.x * APB;
    int count = min(APB, NA - a0);
    if (count <= 0) return;
    size_t baseoff = ((size_t)img * NA + a0) * ROW;
    const float* base = pred + baseoff;
    __shared__ __align__(16) float tile[APB * ROW];
    int nfloat = count * ROW;
    if ((baseoff & 3) == 0) {
        int nvec = nfloat >> 2;
        const float4* b4 = (const float4*)base;
        float4* t4 = (float4*)tile;
        for (int i = threadIdx.x; i < nvec; i += blockDim.x) t4[i] = b4[i];
        for (int i = (nvec << 2) + threadIdx.x; i < nfloat; i += blockDim.x)
            tile[i] = base[i];
    } else {
        for (int i = threadIdx.x; i < nfloat; i += blockDim.x) tile[i] = base[i];
    }
    __syncthreads();
    int t = threadIdx.x;
    if (t < count) {
        const float* r = tile + t * ROW;
        float obj = r[4];
        float maxv = -1.0f; int cl = 0;
        for (int j = 0; j < NCLS; ++j) {
            float v = r[5 + j] * obj;
            if (v > maxv) { maxv = v; cl = j; }   // first-max == jnp.argmax
        }
        bool valid = (obj > CONF_THR) && (maxv > CONF_THR);
        float score = valid ? maxv : -1.0f;
        size_t g = (size_t)img * NA + a0 + t;
        key[g] = f2s(score);
        cls[g] = (u32)cl;
    }
}

// ---------------- K2: exact top-1024 (radix select + bitonic) ----------------
// Contention-free: match-any wave aggregation for histograms, wave-aggregated
// barrier-free compaction. Tie exactness: T (exact dup count of cut value,
// read from level-3 hist) == R => ties order-free (final sort orders by idx);
// T > R (pathological) => exact sequential single-wave tie pass.
__global__ __launch_bounds__(1024) void k_topk(const u32* __restrict__ key,
        u32* __restrict__ top_idx, float* __restrict__ top_score, int NA) {
    int img = blockIdx.x;
    const u32* kb = key + (size_t)img * NA;
    __shared__ u32 hist[256];
    __shared__ u32 sfx[256];
    __shared__ int sh_d;
    __shared__ u32 sh_t;
    __shared__ u32 gcnt;
    __shared__ u64 skey[TOPK];
    int tid = threadIdx.x;
    int lane = tid & 63;
    u64 lanemask = (1ull << lane) - 1ull;
    u32 prefix = 0, target = TOPK;
    for (int level = 0; level < 4; ++level) {
        int shift = 24 - 8 * level;
        if (tid < 256) hist[tid] = 0;
        __syncthreads();
        for (int idx0 = 0; idx0 < NA; idx0 += 1024) {
            int idx = idx0 + tid;
            bool inb = idx < NA;
            u32 k = inb ? kb[idx] : 0u;
            bool in = inb && ((level == 0) || ((k >> (shift + 8)) == prefix));
            u32 d = (k >> shift) & 0xFFu;
            // match-any: peers = active lanes in this wave with same digit
            u64 peers = __ballot(in);
#pragma unroll
            for (int bit = 0; bit < 8; ++bit) {
                u64 bb = __ballot((d >> bit) & 1u);
                peers &= ((d >> bit) & 1u) ? bb : ~bb;
            }
            if (in) {
                int leader = (int)(__ffsll((long long)peers) - 1);
                if (lane == leader) atomicAdd(&hist[d], (u32)__popcll(peers));
            }
        }
        __syncthreads();
        // parallel suffix-sum: sfx[d] = sum_{k>=d} hist[k]
        if (tid < 256) sfx[tid] = hist[tid];
        __syncthreads();
        for (int off = 1; off < 256; off <<= 1) {
            u32 v = 0;
            if (tid < 256) {
                v = sfx[tid];
                if (tid + off < 256) v += sfx[tid + off];
            }
            __syncthreads();
            if (tid < 256) sfx[tid] = v;
            __syncthreads();
        }
        // largest d with sfx[d] >= target; new target = target - sfx[d+1]
        if (tid < 256) {
            u32 S = sfx[tid];
            u32 Snext = (tid == 255) ? 0u : sfx[tid + 1];
            if (S >= target && Snext < target) { sh_d = tid; sh_t = target - Snext; }
        }
        __syncthreads();
        prefix = (prefix << 8) | (u32)sh_d;
        target = sh_t;
        __syncthreads();
    }
    u32 cutv = prefix;
    u32 R = target;                          // ties to take (smallest-index first)
    u32 T = hist[cutv & 0xFFu];              // level-3 bin == exact-dup count of cutv
    if (tid == 0) gcnt = 0;
    __syncthreads();
    bool takeTies = (T == R);
    // barrier-free wave-aggregated scatter (order fixed later by sort)
    for (int c0 = 0; c0 < NA; c0 += 1024) {
        int idx = c0 + tid;
        bool inb = idx < NA;
        u32 k = inb ? kb[idx] : 0u;
        bool put = inb && ((k > cutv) || (takeTies && k == cutv));
        u64 ball = __ballot(put);
        if (ball) {
            int leader = (int)(__ffsll((long long)ball) - 1);
            u32 base = 0;
            if (lane == leader) base = atomicAdd(&gcnt, (u32)__popcll(ball));
            base = __shfl(base, leader);
            if (put)
                skey[base + (u32)__popcll(ball & lanemask)] =
                    ((u64)k << 32) | (u64)(u32)(NA - 1 - idx);
        }
    }
    __syncthreads();
    if (!takeTies) {
        // exact path: R smallest-index ties, single wave, sequential ranks
        u32 G = gcnt;                        // == TOPK - R
        if (tid < 64) {
            u32 cnt = 0;
            for (int c0 = 0; c0 < NA; c0 += 64) {
                int idx = c0 + tid;
                bool ist = (idx < NA) && (kb[idx] == cutv);
                u64 ball = __ballot(ist);
                u32 rank = cnt + (u32)__popcll(ball & lanemask);
                if (ist && rank < R)
                    skey[G + rank] = ((u64)cutv << 32) | (u64)(u32)(NA - 1 - idx);
                cnt += (u32)__popcll(ball);
                if (cnt >= R) break;
            }
        }
        __syncthreads();
    }
    // bitonic sort, descending by (score, then smaller idx first)
    for (int k2 = 2; k2 <= TOPK; k2 <<= 1) {
        for (int j = k2 >> 1; j > 0; j >>= 1) {
            int i = tid, ixj = i ^ j;
            if (ixj > i) {
                u64 a = skey[i], b = skey[ixj];
                bool desc = ((i & k2) == 0);
                if ((a < b) == desc) { skey[i] = b; skey[ixj] = a; }
            }
            __syncthreads();
        }
    }
    u64 kk = skey[tid];
    u32 aidx = (u32)(NA - 1) - (u32)(kk & 0xFFFFFFFFull);
    top_idx[img * TOPK + tid] = aidx;
    top_score[img * TOPK + tid] = s2f((u32)(kk >> 32));
}

// ---------------- K3: gather boxes/cls for selected ----------------
__global__ void k_prep(const float* __restrict__ pred, const u32* __restrict__ cls,
        const u32* __restrict__ top_idx,
        float* __restrict__ boxk, float* __restrict__ nmsbox,
        float* __restrict__ clsf, int NA) {
#pragma clang fp contract(off)
    int img = blockIdx.y;
    int t = blockIdx.x * blockDim.x + threadIdx.x;
    if (t >= TOPK) return;
    int g = img * TOPK + t;
    u32 aidx = top_idx[g];
    const float* r = pred + ((size_t)img * NA + aidx) * ROW;
    float cx = r[0], cy = r[1], w = r[2], h = r[3];
    float hw = w * 0.5f, hh = h * 0.5f;
    float x1 = cx - hw, y1 = cy - hh, x2 = cx + hw, y2 = cy + hh;
    u32 c = cls[(size_t)img * NA + aidx];
    float off = (float)c * MAX_WH_F;
    boxk[g * 4 + 0] = x1; boxk[g * 4 + 1] = y1;
    boxk[g * 4 + 2] = x2; boxk[g * 4 + 3] = y2;
    nmsbox[g * 4 + 0] = x1 + off; nmsbox[g * 4 + 1] = y1 + off;
    nmsbox[g * 4 + 2] = x2 + off; nmsbox[g * 4 + 3] = y2 + off;
    clsf[g] = (float)c;
}

// ---------------- K4: 1024x1024 IoU suppression bitmask ----------------
__global__ __launch_bounds__(1024) void k_mask(const float* __restrict__ nmsbox,
        u64* __restrict__ mask) {
#pragma clang fp contract(off)
    int img = blockIdx.y;
    __shared__ float bx[TOPK + 32], by[TOPK + 32], bX[TOPK + 32], bY[TOPK + 32], ar[TOPK + 32];
    int tid = threadIdx.x;
    {
        const float4* nb = (const float4*)(nmsbox + (size_t)img * TOPK * 4);
        float4 b = nb[tid];
        int pi = tid + (tid >> 5);
        bx[pi] = b.x; by[pi] = b.y; bX[pi] = b.z; bY[pi] = b.w;
        ar[pi] = (b.z - b.x) * (b.w - b.y);
    }
    __syncthreads();
    int i = blockIdx.x * 64 + (tid >> 4);
    int w = tid & 15;
    int pi = i + (i >> 5);
    float ax = bx[pi], ay = by[pi], aX = bX[pi], aY = bY[pi], aa = ar[pi];
    u64 bits = 0;
    for (int jj = 0; jj < 64; ++jj) {
        int j = (w << 6) + jj;
        if (j > i) {
            int pj = j + (j >> 5);
            float ltx = fmaxf(ax, bx[pj]);
            float lty = fmaxf(ay, by[pj]);
            float rbx = fminf(aX, bX[pj]);
            float rby = fminf(aY, bY[pj]);
            float ww = fmaxf(rbx - ltx, 0.0f);
            float hh = fmaxf(rby - lty, 0.0f);
            float inter = ww * hh;
            float denom = ((aa + ar[pj]) - inter) + 1e-9f;  // exact np expr order
            float iou = inter / denom;
            if (iou > IOU_THR) bits |= (1ull << jj);
        }
    }
    mask[((size_t)img * TOPK + i) * 16 + w] = bits;
}

// ---------------- K5: sequential greedy reduction, 1 wave/image ----------------
// Keep decision via ballot (v_cmp -> sgpr, ~5 cyc) instead of __shfl
// (2x ds_bpermute, ~240 cyc serial chain). Loads stay 32 deep.
__global__ __launch_bounds__(64) void k_nms(const u64* __restrict__ mask,
        const float* __restrict__ top_score,
        u32* __restrict__ sel, u32* __restrict__ selcnt) {
    int img = blockIdx.x;
    int lane = threadIdx.x;
    const u64* mrow = mask + (size_t)img * TOPK * 16;
    // nvalid = count of scores > CONF_THR (scores sorted desc -> prefix)
    int cnt = 0;
    for (int k = 0; k < TOPK / 64; ++k) {
        float s = top_score[img * TOPK + k * 64 + lane];
        cnt += (s > CONF_THR) ? 1 : 0;
    }
    for (int off = 32; off > 0; off >>= 1) cnt += __shfl_down(cnt, off);
    int nvalid = __shfl(cnt, 0);

    bool ld = lane < 16;
    u64 rem = 0;                       // lane w<16 owns suppressed word w
    u64 buf[NMS_P];
#pragma unroll
    for (int k = 0; k < NMS_P; ++k)
        buf[k] = ld ? mrow[(size_t)k * 16 + lane] : 0ull;
    int kept = 0;
    for (int base = 0; base < TOPK; base += NMS_P) {
        if (base >= nvalid || kept >= MAX_DET) break;
#pragma unroll
        for (int k = 0; k < NMS_P; ++k) {
            int i = base + k;
            u64 roww = buf[k];
            int pf = i + NMS_P;
            buf[k] = (ld && pf < TOPK) ? mrow[(size_t)pf * 16 + lane] : 0ull;
            if (i < nvalid && kept < MAX_DET) {
                bool notsup = (lane == (i >> 6)) && !((rem >> (i & 63)) & 1ull);
                if (__ballot(notsup) != 0ull) {
                    if (lane == 0) sel[img * MAX_DET + kept] = (u32)i;
                    rem |= roww;       // roww has only bits j>i
                    ++kept;
                }
            }
        }
    }
    if (lane == 0) selcnt[img] = (u32)kept;
}

// ---------------- K6: write all outputs (d_out re-poisoned each launch) ----------------
__global__ void k_out(const float* __restrict__ logits,
        const u32* __restrict__ top_idx, const float* __restrict__ top_score,
        const float* __restrict__ boxk, const float* __restrict__ clsf,
        const u32* __restrict__ sel, const u32* __restrict__ selcnt,
        float* __restrict__ out, int NA, int B) {
    int img = blockIdx.y;
    int t = blockIdx.x;
    int tid = threadIdx.x;
    u32 K = selcnt[img];
    size_t detoff = ((size_t)img * MAX_DET + t) * 6;
    size_t voff = (size_t)B * MAX_DET * 6 + (size_t)img * MAX_DET + t;
    size_t loff = (size_t)B * MAX_DET * 7 + ((size_t)img * MAX_DET + t) * NCLS;
    if ((u32)t < K) {
        int slot = (int)sel[img * MAX_DET + t];
        int g = img * TOPK + slot;
        u32 aidx = top_idx[g];
        if (tid < NCLS)      out[loff + tid] = logits[((size_t)img * NA + aidx) * NCLS + tid];
        else if (tid < 84)   out[detoff + (tid - 80)] = boxk[(size_t)g * 4 + (tid - 80)];
        else if (tid == 84)  out[detoff + 4] = top_score[g];
        else if (tid == 85)  out[detoff + 5] = clsf[g];
        else if (tid == 86)  out[voff] = 1.0f;
    } else {
        if (tid < NCLS)      out[loff + tid] = 0.0f;
        else if (tid < 86)   out[detoff + (tid - 80)] = 0.0f;
        else if (tid == 86)  out[voff] = 0.0f;
    }
}

extern "C" void kernel_launch(void* const* d_in, const int* in_sizes, int n_in,
                              void* d_out, int out_size, void* d_ws, size_t ws_size,
                              hipStream_t stream) {
    const float* pred = (const float*)d_in[0];
    const float* logits = (const float*)d_in[1];
    float* out = (float*)d_out;
    const int B = out_size / (MAX_DET * (6 + 1 + NCLS));   // 16
    const int NA = in_sizes[0] / (B * ROW);                // 25200

    char* p = (char*)d_ws;
    auto alloc = [&](size_t bytes) -> void* {
        void* r = (void*)p;
        p += (bytes + 255) & ~(size_t)255;
        return r;
    };
    u32* key       = (u32*)alloc((size_t)B * NA * 4);
    u32* cls       = (u32*)alloc((size_t)B * NA * 4);
    u32* top_idx   = (u32*)alloc((size_t)B * TOPK * 4);
    float* top_scr = (float*)alloc((size_t)B * TOPK * 4);
    float* boxk    = (float*)alloc((size_t)B * TOPK * 16);
    float* nmsbox  = (float*)alloc((size_t)B * TOPK * 16);
    float* clsf    = (float*)alloc((size_t)B * TOPK * 4);
    u64* mask      = (u64*)alloc((size_t)B * TOPK * 16 * 8);
    u32* sel       = (u32*)alloc((size_t)B * MAX_DET * 4);
    u32* selcnt    = (u32*)alloc((size_t)B * 4);

    k_score<<<dim3((NA + APB - 1) / APB, B), 256, 0, stream>>>(pred, key, cls, NA);
    k_topk<<<dim3(B), 1024, 0, stream>>>(key, top_idx, top_scr, NA);
    k_prep<<<dim3(TOPK / 256, B), 256, 0, stream>>>(pred, cls, top_idx, boxk, nmsbox, clsf, NA);
    k_mask<<<dim3(TOPK / 64, B), 1024, 0, stream>>>(nmsbox, mask);
    k_nms<<<dim3(B), 64, 0, stream>>>(mask, top_scr, sel, selcnt);
    k_out<<<dim3(MAX_DET, B), 128, 0, stream>>>(logits, top_idx, top_scr, boxk, clsf,
                                                sel, selcnt, out, NA, B);
}

// Round 4
// 368.054 us; speedup vs baseline: 1.2357x; 1.2357x over previous
//
#include <hip/hip_runtime.h>
#include <stdint.h>

#define CONF_THR 0.6f
#define IOU_THR  0.45f
#define MAX_WH_F 4096.0f
#define TOPK     1024
#define MAX_DET  300
#define NCLS     80
#define ROW      85
#define APB      128   // anchors per block in K1
#define RING     16    // k_nms register prefetch ring (32 VGPRs - no spill)

typedef unsigned int u32;
typedef unsigned long long u64;

__device__ __forceinline__ u32 f2s(float f) {
    u32 b = __float_as_uint(f);
    return b ^ ((u32)((int)b >> 31) | 0x80000000u);
}
__device__ __forceinline__ float s2f(u32 k) {
    u32 b = (k & 0x80000000u) ? (k ^ 0x80000000u) : ~k;
    return __uint_as_float(b);
}

// ---------------- K1: per-anchor score/cls ----------------
__global__ __launch_bounds__(256) void k_score(const float* __restrict__ pred,
        u32* __restrict__ key, u32* __restrict__ cls, int NA) {
#pragma clang fp contract(off)
    int img = blockIdx.y;
    int a0 = blockIdx.x * APB;
    int count = min(APB, NA - a0);
    if (count <= 0) return;
    size_t baseoff = ((size_t)img * NA + a0) * ROW;
    const float* base = pred + baseoff;
    __shared__ __align__(16) float tile[APB * ROW];
    int nfloat = count * ROW;
    if ((baseoff & 3) == 0) {
        int nvec = nfloat >> 2;
        const float4* b4 = (const float4*)base;
        float4* t4 = (float4*)tile;
        for (int i = threadIdx.x; i < nvec; i += blockDim.x) t4[i] = b4[i];
        for (int i = (nvec << 2) + threadIdx.x; i < nfloat; i += blockDim.x)
            tile[i] = base[i];
    } else {
        for (int i = threadIdx.x; i < nfloat; i += blockDim.x) tile[i] = base[i];
    }
    __syncthreads();
    int t = threadIdx.x;
    if (t < count) {
        const float* r = tile + t * ROW;
        float obj = r[4];
        float maxv = -1.0f; int cl = 0;
        for (int j = 0; j < NCLS; ++j) {
            float v = r[5 + j] * obj;
            if (v > maxv) { maxv = v; cl = j; }   // first-max == jnp.argmax
        }
        bool valid = (obj > CONF_THR) && (maxv > CONF_THR);
        float score = valid ? maxv : -1.0f;
        size_t g = (size_t)img * NA + a0 + t;
        key[g] = f2s(score);
        cls[g] = (u32)cl;
    }
}

// ---------------- K2: exact top-1024 (radix select + bitonic) + fused prep ----
// v4: per-wave private hists (no cross-wave contention), match-any only on the
// dense level 0, single-wave shfl suffix-scan (no barrier ladder), bitonic with
// wave-local (j<64) steps barrier-free, k_prep fused into epilogue.
__global__ __launch_bounds__(1024) void k_topk(const u32* __restrict__ key,
        const float* __restrict__ pred, const u32* __restrict__ cls,
        u32* __restrict__ top_idx, float* __restrict__ top_score,
        float* __restrict__ boxk, float* __restrict__ nmsbox,
        float* __restrict__ clsf, int NA) {
#pragma clang fp contract(off)
    int img = blockIdx.x;
    const u32* kb = key + (size_t)img * NA;
    __shared__ u32 whist[16 * 256];
    __shared__ u32 hfin[256];
    __shared__ int sh_d;
    __shared__ u32 sh_t;
    __shared__ u32 gcnt;
    __shared__ u64 skey[TOPK];
    int tid = threadIdx.x;
    int wid = tid >> 6, lane = tid & 63;
    u64 lanemask = (1ull << lane) - 1ull;
    u32 prefix = 0, target = TOPK;
    for (int level = 0; level < 4; ++level) {
        int shift = 24 - 8 * level;
        for (int i = tid; i < 16 * 256; i += 1024) whist[i] = 0;
        __syncthreads();
        for (int idx0 = 0; idx0 < NA; idx0 += 1024) {
            int idx = idx0 + tid;
            bool inb = idx < NA;
            u32 k = inb ? kb[idx] : 0u;
            bool in = inb && ((level == 0) || ((k >> (shift + 8)) == prefix));
            u32 d = (k >> shift) & 0xFFu;
            if (level == 0) {
                // match-any: hot-digit dedup (uniform data -> ~2 digits/wave)
                u64 peers = __ballot(in);
#pragma unroll
                for (int bit = 0; bit < 8; ++bit) {
                    u64 bb = __ballot((d >> bit) & 1u);
                    peers &= ((d >> bit) & 1u) ? bb : ~bb;
                }
                if (in) {
                    int leader = (int)(__ffsll((long long)peers) - 1);
                    if (lane == leader)
                        atomicAdd(&whist[(wid << 8) | d], (u32)__popcll(peers));
                }
            } else {
                if (in) atomicAdd(&whist[(wid << 8) | d], 1u);  // sparse levels
            }
        }
        __syncthreads();
        if (tid < 256) {
            u32 s = 0;
#pragma unroll
            for (int w = 0; w < 16; ++w) s += whist[(w << 8) | tid];
            hfin[tid] = s;
        }
        __syncthreads();
        if (tid < 64) {
            // suffix-scan of 256 bins in one wave: lane l owns bins 4l..4l+3
            u32 h0 = hfin[4 * tid], h1 = hfin[4 * tid + 1];
            u32 h2 = hfin[4 * tid + 2], h3 = hfin[4 * tid + 3];
            u32 s = h0 + h1 + h2 + h3;
            u32 t = s;
#pragma unroll
            for (int off = 1; off < 64; off <<= 1) {
                u32 o = (u32)__shfl_down((int)t, off);
                if (tid + off < 64) t += o;
            }
            u32 S0 = t, S1 = t - h0, S2 = S1 - h1, S3 = S2 - h2, S4 = t - s;
            u32 tg = target;
            if (S0 >= tg && S1 < tg) { sh_d = 4 * tid;     sh_t = tg - S1; }
            if (S1 >= tg && S2 < tg) { sh_d = 4 * tid + 1; sh_t = tg - S2; }
            if (S2 >= tg && S3 < tg) { sh_d = 4 * tid + 2; sh_t = tg - S3; }
            if (S3 >= tg && S4 < tg) { sh_d = 4 * tid + 3; sh_t = tg - S4; }
        }
        __syncthreads();
        prefix = (prefix << 8) | (u32)sh_d;
        target = sh_t;
    }
    u32 cutv = prefix;
    u32 R = target;                          // ties to take (smallest-index first)
    u32 T = hfin[cutv & 0xFFu];              // level-3 bin == exact-dup count of cutv
    if (tid == 0) gcnt = 0;
    __syncthreads();
    bool takeTies = (T == R);
    // barrier-free wave-aggregated scatter (order fixed later by sort)
    for (int c0 = 0; c0 < NA; c0 += 1024) {
        int idx = c0 + tid;
        bool inb = idx < NA;
        u32 k = inb ? kb[idx] : 0u;
        bool put = inb && ((k > cutv) || (takeTies && k == cutv));
        u64 ball = __ballot(put);
        if (ball) {
            int leader = (int)(__ffsll((long long)ball) - 1);
            u32 base = 0;
            if (lane == leader) base = atomicAdd(&gcnt, (u32)__popcll(ball));
            base = __shfl(base, leader);
            if (put)
                skey[base + (u32)__popcll(ball & lanemask)] =
                    ((u64)k << 32) | (u64)(u32)(NA - 1 - idx);
        }
    }
    __syncthreads();
    if (!takeTies) {
        // exact path: R smallest-index ties, single wave, sequential ranks
        u32 G = gcnt;                        // == TOPK - R
        if (tid < 64) {
            u32 cnt = 0;
            for (int c0 = 0; c0 < NA; c0 += 64) {
                int idx = c0 + tid;
                bool ist = (idx < NA) && (kb[idx] == cutv);
                u64 ball = __ballot(ist);
                u32 rank = cnt + (u32)__popcll(ball & lanemask);
                if (ist && rank < R)
                    skey[G + rank] = ((u64)cutv << 32) | (u64)(u32)(NA - 1 - idx);
                cnt += (u32)__popcll(ball);
                if (cnt >= R) break;
            }
        }
        __syncthreads();
    }
    // bitonic sort, descending by (score, then smaller idx first).
    // j<64 pairs stay inside one 64-thread wave -> lockstep, no barrier needed.
    int jprev = 0;
    for (int k2 = 2; k2 <= TOPK; k2 <<= 1) {
        for (int j = k2 >> 1; j > 0; j >>= 1) {
            if (j >= 64 || jprev >= 64) __syncthreads();
            int i = tid, ixj = i ^ j;
            if (ixj > i) {
                u64 a = skey[i], b = skey[ixj];
                bool desc = ((i & k2) == 0);
                if ((a < b) == desc) { skey[i] = b; skey[ixj] = a; }
            }
            jprev = j;
        }
    }
    __syncthreads();
    u64 kk = skey[tid];
    u32 aidx = (u32)(NA - 1) - (u32)(kk & 0xFFFFFFFFull);
    float sc = s2f((u32)(kk >> 32));
    int g = img * TOPK + tid;
    top_idx[g] = aidx;
    top_score[g] = sc;
    // fused k_prep
    const float* r = pred + ((size_t)img * NA + aidx) * ROW;
    float cx = r[0], cy = r[1], w4 = r[2], h4 = r[3];
    float hw = w4 * 0.5f, hh = h4 * 0.5f;
    float x1 = cx - hw, y1 = cy - hh, x2 = cx + hw, y2 = cy + hh;
    u32 c = cls[(size_t)img * NA + aidx];
    float off = (float)c * MAX_WH_F;
    boxk[g * 4 + 0] = x1; boxk[g * 4 + 1] = y1;
    boxk[g * 4 + 2] = x2; boxk[g * 4 + 3] = y2;
    nmsbox[g * 4 + 0] = x1 + off; nmsbox[g * 4 + 1] = y1 + off;
    nmsbox[g * 4 + 2] = x2 + off; nmsbox[g * 4 + 3] = y2 + off;
    clsf[g] = (float)c;
}

// ---------------- K4: 1024x1024 IoU suppression bitmask ----------------
__global__ __launch_bounds__(1024) void k_mask(const float* __restrict__ nmsbox,
        u64* __restrict__ mask) {
#pragma clang fp contract(off)
    int img = blockIdx.y;
    __shared__ float bx[TOPK + 32], by[TOPK + 32], bX[TOPK + 32], bY[TOPK + 32], ar[TOPK + 32];
    int tid = threadIdx.x;
    {
        const float4* nb = (const float4*)(nmsbox + (size_t)img * TOPK * 4);
        float4 b = nb[tid];
        int pi = tid + (tid >> 5);
        bx[pi] = b.x; by[pi] = b.y; bX[pi] = b.z; bY[pi] = b.w;
        ar[pi] = (b.z - b.x) * (b.w - b.y);
    }
    __syncthreads();
    int i = blockIdx.x * 64 + (tid >> 4);
    int w = tid & 15;
    int pi = i + (i >> 5);
    float ax = bx[pi], ay = by[pi], aX = bX[pi], aY = bY[pi], aa = ar[pi];
    u64 bits = 0;
    for (int jj = 0; jj < 64; ++jj) {
        int j = (w << 6) + jj;
        if (j > i) {
            int pj = j + (j >> 5);
            float ltx = fmaxf(ax, bx[pj]);
            float lty = fmaxf(ay, by[pj]);
            float rbx = fminf(aX, bX[pj]);
            float rby = fminf(aY, bY[pj]);
            float ww = fmaxf(rbx - ltx, 0.0f);
            float hh = fmaxf(rby - lty, 0.0f);
            float inter = ww * hh;
            float denom = ((aa + ar[pj]) - inter) + 1e-9f;  // exact np expr order
            float iou = inter / denom;
            if (iou > IOU_THR) bits |= (1ull << jj);
        }
    }
    mask[((size_t)img * TOPK + i) * 16 + w] = bits;
}

// ---------------- K5: sequential greedy, 1 wave + 15 L2-warming waves --------
// Ring of 16 u64 = 32 VGPRs (no spill; R2/R3's buf[32]=64 VGPRs spilled to
// scratch at VGPR_Count=72 -> ~235cyc/iter scratch round-trip). Keep bits go
// into per-block bitmasks; sel[] extracted after the loop (matches reference:
// keep computed for all i, first 300 kept in slot order are the output).
__global__ __launch_bounds__(1024) void k_nms(const u64* __restrict__ mask,
        const float* __restrict__ top_score,
        u32* __restrict__ sel, u32* __restrict__ selcnt, u32* __restrict__ dummy) {
    __shared__ u32 s_nvalid;
    __shared__ u64 keepw[16];
    int img = blockIdx.x;
    int tid = threadIdx.x;
    int lane = tid & 63;
    if (tid == 0) s_nvalid = 0;
    if (tid < 16) keepw[tid] = 0;
    __syncthreads();
    {
        float s = top_score[img * TOPK + tid];
        u64 b = __ballot(s > CONF_THR);
        if (lane == 0) atomicAdd(&s_nvalid, (u32)__popcll(b));
    }
    __syncthreads();
    const u64* mrow = mask + (size_t)img * TOPK * 16;
    if (tid >= 64) {
        // waves 1-15: pull the 128 KB mask into this CU's L1/local L2
        const uint4* m16 = (const uint4*)mrow;          // 8192 vec16
        u32 acc = 0;
        for (int i = tid - 64; i < 8192; i += 960) {
            uint4 v = m16[i];
            acc ^= v.x ^ v.y ^ v.z ^ v.w;
        }
        if (acc == 0xDEADBEEFu) *dummy = acc;           // keep loads alive
        return;
    }
    // wave 0: serial greedy reduction
    int nvalid = (int)s_nvalid;
    bool ld = lane < 16;
    u64 rem = 0;                       // lane w<16 owns suppressed word w
    u64 pf[RING];
#pragma unroll
    for (int k = 0; k < RING; ++k)
        pf[k] = ld ? mrow[(size_t)k * 16 + lane] : 0ull;
    int nblk = (nvalid + 63) >> 6;
    int kept_total = 0;
    for (int blk = 0; blk < nblk; ++blk) {
        u64 kw = 0;
        int base = blk << 6;
#pragma unroll 16
        for (int t = 0; t < 64; ++t) {
            int i = base + t;
            u64 roww = pf[i & (RING - 1)];
            int nx = i + RING;
            pf[i & (RING - 1)] = (ld && nx < TOPK) ? mrow[(size_t)nx * 16 + lane] : 0ull;
            bool notsup = (lane == (i >> 6)) && !((rem >> (i & 63)) & 1ull);
            if (__ballot(notsup) != 0ull) {            // wave-uniform keep
                rem |= roww;                           // roww has only bits j>i
                kw |= (1ull << t);
            }
        }
        int over = nvalid - base;
        if (over < 64) kw &= (over <= 0) ? 0ull : ((1ull << over) - 1ull);
        if (lane == 0) keepw[blk] = kw;
        kept_total += (int)__popcll(kw);
        if (kept_total >= MAX_DET) break;              // rest can't affect first 300
    }
    // extract first <=300 kept slots
    if (lane < 16) {
        u64 kw = keepw[lane];
        u32 rank = 0;
        for (int m = 0; m < 16; ++m)
            if (m < lane) rank += (u32)__popcll(keepw[m]);
        while (kw) {
            int b = (int)__ffsll((long long)kw) - 1;
            if (rank < MAX_DET) sel[img * MAX_DET + rank] = (u32)((lane << 6) + b);
            ++rank;
            kw &= kw - 1;
        }
    }
    if (lane == 0) selcnt[img] = (u32)min(kept_total, MAX_DET);
}

// ---------------- K6: write all outputs (d_out re-poisoned each launch) ------
__global__ void k_out(const float* __restrict__ logits,
        const u32* __restrict__ top_idx, const float* __restrict__ top_score,
        const float* __restrict__ boxk, const float* __restrict__ clsf,
        const u32* __restrict__ sel, const u32* __restrict__ selcnt,
        float* __restrict__ out, int NA, int B) {
    int img = blockIdx.y;
    int t = blockIdx.x;
    int tid = threadIdx.x;
    u32 K = selcnt[img];
    size_t detoff = ((size_t)img * MAX_DET + t) * 6;
    size_t voff = (size_t)B * MAX_DET * 6 + (size_t)img * MAX_DET + t;
    size_t loff = (size_t)B * MAX_DET * 7 + ((size_t)img * MAX_DET + t) * NCLS;
    if ((u32)t < K) {
        int slot = (int)sel[img * MAX_DET + t];
        int g = img * TOPK + slot;
        u32 aidx = top_idx[g];
        if (tid < NCLS)      out[loff + tid] = logits[((size_t)img * NA + aidx) * NCLS + tid];
        else if (tid < 84)   out[detoff + (tid - 80)] = boxk[(size_t)g * 4 + (tid - 80)];
        else if (tid == 84)  out[detoff + 4] = top_score[g];
        else if (tid == 85)  out[detoff + 5] = clsf[g];
        else if (tid == 86)  out[voff] = 1.0f;
    } else {
        if (tid < NCLS)      out[loff + tid] = 0.0f;
        else if (tid < 86)   out[detoff + (tid - 80)] = 0.0f;
        else if (tid == 86)  out[voff] = 0.0f;
    }
}

extern "C" void kernel_launch(void* const* d_in, const int* in_sizes, int n_in,
                              void* d_out, int out_size, void* d_ws, size_t ws_size,
                              hipStream_t stream) {
    const float* pred = (const float*)d_in[0];
    const float* logits = (const float*)d_in[1];
    float* out = (float*)d_out;
    const int B = out_size / (MAX_DET * (6 + 1 + NCLS));   // 16
    const int NA = in_sizes[0] / (B * ROW);                // 25200

    char* p = (char*)d_ws;
    auto alloc = [&](size_t bytes) -> void* {
        void* r = (void*)p;
        p += (bytes + 255) & ~(size_t)255;
        return r;
    };
    u32* key       = (u32*)alloc((size_t)B * NA * 4);
    u32* cls       = (u32*)alloc((size_t)B * NA * 4);
    u32* top_idx   = (u32*)alloc((size_t)B * TOPK * 4);
    float* top_scr = (float*)alloc((size_t)B * TOPK * 4);
    float* boxk    = (float*)alloc((size_t)B * TOPK * 16);
    float* nmsbox  = (float*)alloc((size_t)B * TOPK * 16);
    float* clsf    = (float*)alloc((size_t)B * TOPK * 4);
    u64* mask      = (u64*)alloc((size_t)B * TOPK * 16 * 8);
    u32* sel       = (u32*)alloc((size_t)B * MAX_DET * 4);
    u32* selcnt    = (u32*)alloc((size_t)(B + 1) * 4);
    u32* dummy     = selcnt + B;

    k_score<<<dim3((NA + APB - 1) / APB, B), 256, 0, stream>>>(pred, key, cls, NA);
    k_topk<<<dim3(B), 1024, 0, stream>>>(key, pred, cls, top_idx, top_scr,
                                         boxk, nmsbox, clsf, NA);
    k_mask<<<dim3(TOPK / 64, B), 1024, 0, stream>>>(nmsbox, mask);
    k_nms<<<dim3(B), 1024, 0, stream>>>(mask, top_scr, sel, selcnt, dummy);
    k_out<<<dim3(MAX_DET, B), 128, 0, stream>>>(logits, top_idx, top_scr, boxk, clsf,
                                                sel, selcnt, out, NA, B);
}